// Round 5
// baseline (332.399 us; speedup 1.0000x reference)
//
#include <hip/hip_runtime.h>

#define BATCH 16
#define NQ    16384      // N = 128*128
#define CH    64         // EMBED
#define NKV   256
#define EPS_LN 1e-5f

typedef __attribute__((ext_vector_type(4))) short bf16x4;
typedef __attribute__((ext_vector_type(8))) short short8;
typedef __attribute__((ext_vector_type(4))) float f32x4;

#define MFMA16(a, b, c) __builtin_amdgcn_mfma_f32_16x16x32_bf16((a), (b), (c), 0, 0, 0)

__device__ __forceinline__ unsigned short f2bf(float f) {
    unsigned int u = __builtin_bit_cast(unsigned int, f);
    u += 0x7FFFu + ((u >> 16) & 1u);   // RNE
    return (unsigned short)(u >> 16);
}
__device__ __forceinline__ unsigned int pk2(float a, float b) {
    return (unsigned int)f2bf(a) | ((unsigned int)f2bf(b) << 16);
}
__device__ __forceinline__ bf16x4 pk4(float a, float b, float c, float d) {
    unsigned long long v = (unsigned long long)pk2(a, b) |
                           ((unsigned long long)pk2(c, d) << 32);
    return __builtin_bit_cast(bf16x4, v);
}
__device__ __forceinline__ short8 cat8(bf16x4 lo, bf16x4 hi) {
    short8 r;
    r[0] = lo[0]; r[1] = lo[1]; r[2] = lo[2]; r[3] = lo[3];
    r[4] = hi[0]; r[5] = hi[1]; r[6] = hi[2]; r[7] = hi[3];
    return r;
}
// k-order permutations (A/B k-slot consistency; see round-3 analysis)
__device__ __forceinline__ int perm64(int c) {   // 64-wide k (d or c dims)
    int cc = c >> 4, q4c = (c >> 2) & 3, e = c & 3;
    return q4c * 16 + (cc >> 1) * 8 + (cc & 1) * 4 + e;
}
__device__ __forceinline__ int perm256(int n) {  // 256-wide k (kv dim)
    int tt = n >> 4, q4n = (n >> 2) & 3, e = n & 3;
    return q4n * 64 + (tt >> 1) * 8 + (tt & 1) * 4 + e;
}

// ---------------- Prep: Wc transpose (natural k-order) + Wq/Wo permuted ----------------
// grid 256: block handles conv_w k-rows [blk*16,+16); blocks 0/1 also do Wq/Wo.
__global__ __launch_bounds__(256) void prep_kernel(
    const float* __restrict__ Wq, const float* __restrict__ Wo,
    const float* __restrict__ conv_w,
    unsigned short* __restrict__ Wq_p, unsigned short* __restrict__ Wo_p,
    unsigned short* __restrict__ Wc_t)   // [64][4096] bf16
{
    __shared__ float tile[16][65];
    const int blk = blockIdx.x;
    const int t = threadIdx.x;
    for (int e = t; e < 1024; e += 256)
        tile[e >> 6][e & 63] = conv_w[(size_t)blk * 1024 + e];
    __syncthreads();
    {
        const int c = t & 63, kq = t >> 6;
        bf16x4 v = pk4(tile[kq * 4 + 0][c], tile[kq * 4 + 1][c],
                       tile[kq * 4 + 2][c], tile[kq * 4 + 3][c]);
        *(bf16x4*)(Wc_t + (size_t)c * 4096 + blk * 16 + kq * 4) = v;
    }
    if (blk < 2) {
        const float* W = blk ? Wo : Wq;
        unsigned short* Wp = blk ? Wo_p : Wq_p;
        for (int i = t; i < 4096; i += 256) {
            int c = i >> 6, d = i & 63;
            Wp[d * 64 + perm64(c)] = f2bf(W[c * 64 + d]);
        }
    }
}

// ---------------- conv partials: GEMM M=16 patches, N=64 couts, K-split 4 ----------------
// grid 1024 = (b*16+ph)*4 + s ; 256 thr = 4 waves, wave = cout-tile.
__global__ __launch_bounds__(256) void conv_part(
    const float* __restrict__ inp,
    const unsigned short* __restrict__ Wc,   // [64][4096]
    float* __restrict__ Cpart)               // [4][B*256][64]
{
    const int blk = blockIdx.x;
    const int s  = blk & 3;
    const int bp = blk >> 2;                  // b*16 + ph
    const int w    = threadIdx.x >> 6;
    const int lane = threadIdx.x & 63;
    const int l15  = lane & 15, q4 = lane >> 4;

    f32x4 acc0 = {0,0,0,0}, acc1 = {0,0,0,0};
    #pragma unroll
    for (int ci = 0; ci < 2; ++ci) {
        const int i = s * 2 + ci;
        const float* rowb = inp + ((size_t)bp * 8 + i) * (128 * 64) + l15 * 512 + q4 * 8;
        const unsigned short* wcb = Wc + (size_t)(w * 16 + l15) * 4096 + i * 512 + q4 * 8;
        #pragma unroll
        for (int kc = 0; kc < 16; ++kc) {
            const float* ap = rowb + (kc >> 1) * 64 + (kc & 1) * 32;
            float4 f0 = *(const float4*)(ap);
            float4 f1 = *(const float4*)(ap + 4);
            short8 af = cat8(pk4(f0.x, f0.y, f0.z, f0.w), pk4(f1.x, f1.y, f1.z, f1.w));
            short8 bf = *(const short8*)(wcb + kc * 32);
            if (kc & 1) acc1 = MFMA16(af, bf, acc1);
            else        acc0 = MFMA16(af, bf, acc0);
        }
    }
    f32x4 accT = acc0 + acc1;
    float* dst = Cpart + ((size_t)s * (BATCH * 256) + bp * 16) * 64 + w * 16 + l15;
    #pragma unroll
    for (int r = 0; r < 4; ++r)
        dst[(q4 * 4 + r) * 64] = accT[r];
}

// ---------------- LN + KV projection, permuted K/V stores ----------------
// grid 256 = b*16+ph, 256 thr.
__global__ __launch_bounds__(256) void ln_kv(
    const float* __restrict__ Cpart,
    const float* __restrict__ conv_b, const float* __restrict__ gamma,
    const float* __restrict__ beta,   const float* __restrict__ Wkv,
    const float* __restrict__ bkv,
    unsigned short* __restrict__ Kb,   // [B,256,64] perm64 d
    unsigned short* __restrict__ Vt)   // [B,64,256] perm256 n
{
    __shared__ float cbuf[16][68];
    __shared__ float yln[16][68];
    const int bp = blockIdx.x;
    const int b  = bp >> 4;
    const int t  = threadIdx.x;
    {
        const int idx = t * 4;
        const float* base = Cpart + ((size_t)bp * 16) * 64 + idx;
        float4 s = *(const float4*)(base);
        #pragma unroll
        for (int sl = 1; sl < 4; ++sl) {
            float4 f = *(const float4*)(base + (size_t)sl * BATCH * 256 * 64);
            s.x += f.x; s.y += f.y; s.z += f.z; s.w += f.w;
        }
        *(float4*)(&cbuf[idx >> 6][idx & 63]) = s;
    }
    __syncthreads();
    {
        const int patch = t >> 4, g = t & 15;
        float x[4], ssum = 0.f;
        #pragma unroll
        for (int cc = 0; cc < 4; ++cc) {
            const int c = g + cc * 16;
            x[cc] = cbuf[patch][c] + conv_b[c];
            ssum += x[cc];
        }
        #pragma unroll
        for (int off = 8; off >= 1; off >>= 1) ssum += __shfl_xor(ssum, off, 16);
        const float mean = ssum * (1.f / 64.f);
        float v2 = 0.f;
        #pragma unroll
        for (int cc = 0; cc < 4; ++cc) { x[cc] -= mean; v2 += x[cc] * x[cc]; }
        #pragma unroll
        for (int off = 8; off >= 1; off >>= 1) v2 += __shfl_xor(v2, off, 16);
        const float rs = rsqrtf(v2 * (1.f / 64.f) + EPS_LN);
        #pragma unroll
        for (int cc = 0; cc < 4; ++cc) {
            const int c = g + cc * 16;
            yln[patch][c] = x[cc] * rs * gamma[c] + beta[c];
        }
    }
    __syncthreads();
    {
        const int col = t & 127, pg = t >> 7;
        #pragma unroll
        for (int pp = 0; pp < 8; ++pp) {
            const int patch = pg * 8 + pp;
            float acc = bkv[col];
            #pragma unroll
            for (int c = 0; c < 64; ++c)
                acc += yln[patch][c] * Wkv[c * 128 + col];
            const int pglob = (bp & 15) * 16 + patch;
            if (col < 64)
                Kb[((size_t)b * 256 + pglob) * 64 + perm64(col)] = f2bf(acc);
            else
                Vt[((size_t)b * 64 + (col - 64)) * 256 + perm256(pglob)] = f2bf(acc);
        }
    }
}

// ---------------- attention: zero-LDS, all-register MFMA chain ----------------
// grid BATCH*NQ/64 blocks, 256 thr = 4 waves; wave w: 16 query rows.
__global__ __launch_bounds__(256, 4) void attn_mfma(
    const float* __restrict__ inp,
    const unsigned short* __restrict__ Wq_p, // [64][64] perm64 cols
    const float* __restrict__ bq,
    const unsigned short* __restrict__ Kb,   // [B,256,64] perm64
    const unsigned short* __restrict__ Vt,   // [B,64,256] perm256
    const unsigned short* __restrict__ Wo_p, // [64][64] perm64 cols
    const float* __restrict__ bo,
    float* __restrict__ out)
{
    const int w    = threadIdx.x >> 6;
    const int lane = threadIdx.x & 63;
    const int l15  = lane & 15;
    const int q4   = lane >> 4;
    const int b    = blockIdx.x >> 8;
    const int m0   = blockIdx.x * 64 + w * 16;

    const f32x4 zero = {0.f, 0.f, 0.f, 0.f};

    // X as B-operand fragments (lane row = m0+l15)
    const float* xr = inp + (size_t)(m0 + l15) * 64 + q4 * 4;
    short8 xb[2];
    {
        float4 f0 = *(const float4*)(xr);
        float4 f1 = *(const float4*)(xr + 16);
        float4 f2 = *(const float4*)(xr + 32);
        float4 f3 = *(const float4*)(xr + 48);
        xb[0] = cat8(pk4(f0.x, f0.y, f0.z, f0.w), pk4(f1.x, f1.y, f1.z, f1.w));
        xb[1] = cat8(pk4(f2.x, f2.y, f2.z, f2.w), pk4(f3.x, f3.y, f3.z, f3.w));
    }
    // Q^T = Wq · X^T
    f32x4 qacc[4];
    #pragma unroll
    for (int t = 0; t < 4; ++t) {
        const unsigned short* wr = Wq_p + (t * 16 + l15) * 64 + q4 * 16;
        short8 w0 = *(const short8*)(wr);
        short8 w1 = *(const short8*)(wr + 8);
        qacc[t] = MFMA16(w1, xb[1], MFMA16(w0, xb[0], zero));
    }
    short8 qb[2];
    {
        bf16x4 q4s[4];
        #pragma unroll
        for (int t = 0; t < 4; ++t) {
            float4 bqv = *(const float4*)(bq + t * 16 + q4 * 4);
            q4s[t] = pk4((qacc[t][0] + bqv.x) * 0.125f, (qacc[t][1] + bqv.y) * 0.125f,
                         (qacc[t][2] + bqv.z) * 0.125f, (qacc[t][3] + bqv.w) * 0.125f);
        }
        qb[0] = cat8(q4s[0], q4s[1]);
        qb[1] = cat8(q4s[2], q4s[3]);
    }
    // S^T = K · Q^T
    const unsigned short* Kbb = Kb + (size_t)b * 256 * 64 + l15 * 64 + q4 * 16;
    f32x4 sacc[16];
    #pragma unroll
    for (int t = 0; t < 16; ++t) {
        const unsigned short* kr = Kbb + t * 1024;
        short8 k0 = *(const short8*)(kr);
        short8 k1 = *(const short8*)(kr + 8);
        sacc[t] = MFMA16(k1, qb[1], MFMA16(k0, qb[0], zero));
    }
    // softmax: per-lane (query m = l15), reduce regs + q4 group
    float mx = -1e30f;
    #pragma unroll
    for (int t = 0; t < 16; ++t)
        #pragma unroll
        for (int r = 0; r < 4; ++r) mx = fmaxf(mx, sacc[t][r]);
    mx = fmaxf(mx, __shfl_xor(mx, 16));
    mx = fmaxf(mx, __shfl_xor(mx, 32));
    float sm = 0.f;
    #pragma unroll
    for (int t = 0; t < 16; ++t)
        #pragma unroll
        for (int r = 0; r < 4; ++r) {
            float p = __expf(sacc[t][r] - mx);
            sacc[t][r] = p;
            sm += p;
        }
    sm += __shfl_xor(sm, 16);
    sm += __shfl_xor(sm, 32);
    const float inv = 1.f / sm;
    short8 pb[8];
    #pragma unroll
    for (int u = 0; u < 8; ++u)
        pb[u] = cat8(pk4(sacc[2*u][0],   sacc[2*u][1],   sacc[2*u][2],   sacc[2*u][3]),
                     pk4(sacc[2*u+1][0], sacc[2*u+1][1], sacc[2*u+1][2], sacc[2*u+1][3]));
    // O^T = V^T · P^T
    const unsigned short* Vtb = Vt + (size_t)b * 64 * 256 + l15 * 256 + q4 * 64;
    short8 ob[2];
    {
        bf16x4 o4s[4];
        #pragma unroll
        for (int dt = 0; dt < 4; ++dt) {
            f32x4 acc = zero;
            const unsigned short* vr = Vtb + dt * 4096;
            #pragma unroll
            for (int u = 0; u < 8; ++u) {
                short8 vf = *(const short8*)(vr + u * 8);
                acc = MFMA16(vf, pb[u], acc);
            }
            o4s[dt] = pk4(acc[0] * inv, acc[1] * inv, acc[2] * inv, acc[3] * inv);
        }
        ob[0] = cat8(o4s[0], o4s[1]);
        ob[1] = cat8(o4s[2], o4s[3]);
    }
    // out^T = Wo · O^T  (+bias, fp32 store)
    float* orow = out + (size_t)(m0 + l15) * 64 + q4 * 4;
    #pragma unroll
    for (int et = 0; et < 4; ++et) {
        const unsigned short* wr = Wo_p + (et * 16 + l15) * 64 + q4 * 16;
        short8 w0 = *(const short8*)(wr);
        short8 w1 = *(const short8*)(wr + 8);
        f32x4 acc = MFMA16(w1, ob[1], MFMA16(w0, ob[0], zero));
        float4 bov = *(const float4*)(bo + et * 16 + q4 * 4);
        float4 res = { acc[0] + bov.x, acc[1] + bov.y, acc[2] + bov.z, acc[3] + bov.w };
        *(float4*)(orow + et * 16) = res;
    }
}

extern "C" void kernel_launch(void* const* d_in, const int* in_sizes, int n_in,
                              void* d_out, int out_size, void* d_ws, size_t ws_size,
                              hipStream_t stream) {
    const float* inp     = (const float*)d_in[0];
    const float* Wq      = (const float*)d_in[1];
    const float* bq      = (const float*)d_in[2];
    const float* Wkv     = (const float*)d_in[3];
    const float* bkv     = (const float*)d_in[4];
    const float* Wo      = (const float*)d_in[5];
    const float* bo      = (const float*)d_in[6];
    const float* conv_w  = (const float*)d_in[7];
    const float* conv_b  = (const float*)d_in[8];
    const float* gamma   = (const float*)d_in[9];
    const float* beta    = (const float*)d_in[10];

    char* ws = (char*)d_ws;
    unsigned short* Kb   = (unsigned short*)(ws);                 // 512 KiB
    unsigned short* Vt   = (unsigned short*)(ws + 524288);        // 512 KiB
    unsigned short* Wq_p = (unsigned short*)(ws + 1048576);       // 8 KiB
    unsigned short* Wo_p = (unsigned short*)(ws + 1056768);       // 8 KiB
    unsigned short* Wc_t = (unsigned short*)(ws + 1064960);       // 512 KiB
    float*          Cpart= (float*)(ws + 1589248);                // 4 MiB

    prep_kernel<<<256, 256, 0, stream>>>(Wq, Wo, conv_w, Wq_p, Wo_p, Wc_t);
    conv_part<<<1024, 256, 0, stream>>>(inp, Wc_t, Cpart);
    ln_kv<<<256, 256, 0, stream>>>(Cpart, conv_b, gamma, beta, Wkv, bkv, Kb, Vt);
    attn_mfma<<<(BATCH * NQ) / 64, 256, 0, stream>>>(inp, Wq_p, bq, Kb, Vt,
                                                     Wo_p, bo, (float*)d_out);
}

// Round 6
// 211.163 us; speedup vs baseline: 1.5741x; 1.5741x over previous
//
#include <hip/hip_runtime.h>

#define BATCH 16
#define NQ    16384      // N = 128*128
#define EPS_LN 1e-5f

typedef __attribute__((ext_vector_type(4))) short bf16x4;
typedef __attribute__((ext_vector_type(8))) short short8;
typedef __attribute__((ext_vector_type(4))) float f32x4;

#define MFMA16(a, b, c) __builtin_amdgcn_mfma_f32_16x16x32_bf16((a), (b), (c), 0, 0, 0)

__device__ __forceinline__ unsigned short f2bf(float f) {
    unsigned int u = __builtin_bit_cast(unsigned int, f);
    u += 0x7FFFu + ((u >> 16) & 1u);   // RNE
    return (unsigned short)(u >> 16);
}
// fast pack: round-half-up via +0x8000 then byte-perm (1 v_perm per 2 elements)
__device__ __forceinline__ unsigned int pk2r(float a, float b) {
    unsigned int ua = __builtin_bit_cast(unsigned int, a) + 0x8000u;
    unsigned int ub = __builtin_bit_cast(unsigned int, b) + 0x8000u;
    return __builtin_amdgcn_perm(ub, ua, 0x07060302u);  // low16=bf(a), high16=bf(b)
}
__device__ __forceinline__ bf16x4 pk4r(float a, float b, float c, float d) {
    unsigned long long v = (unsigned long long)pk2r(a, b) |
                           ((unsigned long long)pk2r(c, d) << 32);
    return __builtin_bit_cast(bf16x4, v);
}
__device__ __forceinline__ short8 cat8(bf16x4 lo, bf16x4 hi) {
    short8 r;
    r[0] = lo[0]; r[1] = lo[1]; r[2] = lo[2]; r[3] = lo[3];
    r[4] = hi[0]; r[5] = hi[1]; r[6] = hi[2]; r[7] = hi[3];
    return r;
}
// k-order permutations (A/B k-slot consistency; round-3 analysis, verified)
__device__ __forceinline__ int perm64(int c) {
    int cc = c >> 4, q4c = (c >> 2) & 3, e = c & 3;
    return q4c * 16 + (cc >> 1) * 8 + (cc & 1) * 4 + e;
}
__device__ __forceinline__ int perm256(int n) {
    int tt = n >> 4, q4n = (n >> 2) & 3, e = n & 3;
    return q4n * 64 + (tt >> 1) * 8 + (tt & 1) * 4 + e;
}

// ---------------- prep: fragment-contiguous weight layouts ----------------
// Wc_f  [nt 0..3][r 0..7][s 0..15][lane 0..63][e 0..7]  (262144 bf16)
// Wkv_f [nt 0..7][s 0..1][lane][e]                      (16384 bf16)
// Wq_p/Wo_p: [d][perm64(c)]                             (4096 each)
// grid 1120 x 256, one element per thread.
__global__ __launch_bounds__(256) void prep_kernel(
    const float* __restrict__ Wq, const float* __restrict__ Wo,
    const float* __restrict__ conv_w, const float* __restrict__ Wkv,
    unsigned short* __restrict__ Wq_p, unsigned short* __restrict__ Wo_p,
    unsigned short* __restrict__ Wc_f, unsigned short* __restrict__ Wkv_f)
{
    int idx = blockIdx.x * 256 + threadIdx.x;
    if (idx < 262144) {
        int e = idx & 7, lane = (idx >> 3) & 63, s = (idx >> 9) & 15;
        int r = (idx >> 13) & 7, nt = (idx >> 16) & 3;
        int k = r * 512 + s * 32 + (lane >> 4) * 8 + e;
        int cout = nt * 16 + (lane & 15);
        Wc_f[idx] = f2bf(conv_w[(size_t)k * 64 + cout]);
    } else if (idx < 278528) {
        int i = idx - 262144;
        int e = i & 7, lane = (i >> 3) & 63, s = (i >> 9) & 1, nt = i >> 10;
        int k = s * 32 + (lane >> 4) * 8 + e;
        int n = nt * 16 + (lane & 15);
        Wkv_f[i] = f2bf(Wkv[(size_t)k * 128 + n]);
    } else if (idx < 282624) {
        int i = idx - 278528;
        int c = i >> 6, d = i & 63;
        Wq_p[d * 64 + perm64(c)] = f2bf(Wq[c * 64 + d]);
    } else {
        int i = idx - 282624;
        int c = i >> 6, d = i & 63;
        Wo_p[d * 64 + perm64(c)] = f2bf(Wo[c * 64 + d]);
    }
}

// ---------------- kv_fused: conv8x8s8 + LN + KV projection, all MFMA ----------------
// grid 256 (= b*16+ph), 256 thr = 4 waves; wave w owns cout-tile w for the conv.
__global__ __launch_bounds__(256) void kv_fused(
    const float* __restrict__ inp,           // [B,16384,64]
    const unsigned short* __restrict__ Wc_f,
    const float* __restrict__ conv_b, const float* __restrict__ gamma,
    const float* __restrict__ beta,
    const unsigned short* __restrict__ Wkv_f, const float* __restrict__ bkv,
    unsigned short* __restrict__ Kb,   // [B,256,64] perm64 d   (round-5 layout)
    unsigned short* __restrict__ Vt)   // [B,64,256] perm256 n
{
    __shared__ unsigned short Xa[2][16][520];  // A-frags of one image row, +8 pad
    __shared__ float Cb[16][68];
    __shared__ unsigned short yb[16][72];

    const int bp = blockIdx.x;
    const int b = bp >> 4, ph = bp & 15;
    const int t = threadIdx.x;
    const int w = t >> 6, lane = t & 63, l15 = lane & 15, q4 = lane >> 4;

    const float* rowbase = inp + (size_t)bp * 8 * 8192;

    float4 rg[8];
    #pragma unroll
    for (int i = 0; i < 8; ++i)
        rg[i] = *(const float4*)(rowbase + i * 1024 + t * 4);

    f32x4 acc0 = {0,0,0,0}, acc1 = {0,0,0,0};
    for (int r = 0; r < 8; ++r) {
        __syncthreads();
        #pragma unroll
        for (int i = 0; i < 8; ++i) {
            const int e0 = i * 1024 + t * 4;
            unsigned int lo = pk2r(rg[i].x, rg[i].y);
            unsigned int hi = pk2r(rg[i].z, rg[i].w);
            *(uint2*)(&Xa[r & 1][e0 >> 9][e0 & 511]) = make_uint2(lo, hi);
        }
        if (r < 7) {
            #pragma unroll
            for (int i = 0; i < 8; ++i)
                rg[i] = *(const float4*)(rowbase + (r + 1) * 8192 + i * 1024 + t * 4);
        }
        __syncthreads();
        const unsigned short* wrow = Wc_f + ((size_t)(w * 8 + r) * 16) * 512 + lane * 8;
        #pragma unroll
        for (int s = 0; s < 16; ++s) {
            short8 af = *(const short8*)&Xa[r & 1][l15][s * 32 + q4 * 8];
            short8 bf = *(const short8*)(wrow + s * 512);
            if (s & 1) acc1 = MFMA16(af, bf, acc1);
            else       acc0 = MFMA16(af, bf, acc0);
        }
    }
    f32x4 accT = acc0 + acc1;
    #pragma unroll
    for (int rr = 0; rr < 4; ++rr)
        Cb[q4 * 4 + rr][w * 16 + l15] = accT[rr];
    __syncthreads();

    // LayerNorm: thread = (patch, g), 4 channels each
    {
        const int patch = t >> 4, g = t & 15;
        float x[4], ssum = 0.f;
        #pragma unroll
        for (int cc = 0; cc < 4; ++cc) {
            const int c = g + cc * 16;
            x[cc] = Cb[patch][c] + conv_b[c];
            ssum += x[cc];
        }
        #pragma unroll
        for (int off = 8; off >= 1; off >>= 1) ssum += __shfl_xor(ssum, off, 16);
        const float mean = ssum * (1.f / 64.f);
        float v2 = 0.f;
        #pragma unroll
        for (int cc = 0; cc < 4; ++cc) { x[cc] -= mean; v2 += x[cc] * x[cc]; }
        #pragma unroll
        for (int off = 8; off >= 1; off >>= 1) v2 += __shfl_xor(v2, off, 16);
        const float rs = rsqrtf(v2 * (1.f / 64.f) + EPS_LN);
        #pragma unroll
        for (int cc = 0; cc < 4; ++cc) {
            const int c = g + cc * 16;
            yb[patch][c] = f2bf(x[cc] * rs * gamma[c] + beta[c]);
        }
    }
    __syncthreads();

    // KV projection: M=16 patches, N=128, K=64 via MFMA; wave w -> n-tiles 2w,2w+1
    #pragma unroll
    for (int tt = 0; tt < 2; ++tt) {
        const int nt = w * 2 + tt;
        f32x4 a2 = {0,0,0,0};
        #pragma unroll
        for (int s = 0; s < 2; ++s) {
            short8 af = *(const short8*)&yb[l15][s * 32 + q4 * 8];
            short8 bf = *(const short8*)(Wkv_f + ((nt * 2 + s) * 64 + lane) * 8);
            a2 = MFMA16(af, bf, a2);
        }
        const int n = nt * 16 + l15;
        const float bias = bkv[n];
        #pragma unroll
        for (int rr = 0; rr < 4; ++rr) {
            const int pg = ph * 16 + q4 * 4 + rr;
            const float v = a2[rr] + bias;
            if (n < 64)
                Kb[((size_t)b * 256 + pg) * 64 + perm64(n)] = f2bf(v);
            else
                Vt[((size_t)b * 64 + (n - 64)) * 256 + perm256(pg)] = f2bf(v);
        }
    }
}

// ---------------- attention: K/V in LDS (rotation-swizzled), register MFMA chain ----------------
// grid 2048 x 512 thr (8 waves); block stages K+V (64 KB) once; wave w: 16 queries.
__global__ __launch_bounds__(512) void attn_mfma(
    const float* __restrict__ inp,
    const unsigned short* __restrict__ Wq_p,
    const float* __restrict__ bq,
    const unsigned short* __restrict__ Kb,   // [B,256,64] perm64
    const unsigned short* __restrict__ Vt,   // [B,64,256] perm256
    const unsigned short* __restrict__ Wo_p,
    const float* __restrict__ bo,
    float* __restrict__ out)
{
    __shared__ unsigned short Klds[16384];   // 256 rows x 128 B, 16B-chunks rotated by (row&7)
    __shared__ unsigned short Vlds[16384];   // 64 rows x 512 B, rotated by (row&7)

    const int tid  = threadIdx.x;
    const int w    = tid >> 6;
    const int lane = tid & 63;
    const int l15  = lane & 15;
    const int q4   = lane >> 4;
    const int b    = blockIdx.x >> 7;
    const int m0   = blockIdx.x * 128 + w * 16;

    // ---- stage K (swizzled) ----
    {
        const int row = tid >> 1, half = tid & 1;
        const unsigned short* src = Kb + (size_t)b * 16384 + row * 64 + half * 32;
        char* dstrow = (char*)Klds + row * 128;
        const int rot = (row & 7) * 16;
        #pragma unroll
        for (int c = 0; c < 4; ++c) {
            short8 v = *(const short8*)(src + c * 8);
            *(short8*)(dstrow + ((half * 64 + c * 16 + rot) & 127)) = v;
        }
    }
    // ---- stage V (swizzled) ----
    {
        const int row = tid >> 3, seg = tid & 7;
        const unsigned short* src = Vt + (size_t)b * 16384 + row * 256 + seg * 32;
        char* dstrow = (char*)Vlds + row * 512;
        const int rot = (row & 7) * 16;
        #pragma unroll
        for (int c = 0; c < 4; ++c) {
            short8 v = *(const short8*)(src + c * 8);
            *(short8*)(dstrow + ((seg * 64 + c * 16 + rot) & 511)) = v;
        }
    }

    const f32x4 zero = {0.f, 0.f, 0.f, 0.f};

    // X fragments (global, dense)
    const float* xr = inp + (size_t)(m0 + l15) * 64 + q4 * 4;
    short8 xb[2];
    {
        float4 f0 = *(const float4*)(xr);
        float4 f1 = *(const float4*)(xr + 16);
        float4 f2 = *(const float4*)(xr + 32);
        float4 f3 = *(const float4*)(xr + 48);
        xb[0] = cat8(pk4r(f0.x, f0.y, f0.z, f0.w), pk4r(f1.x, f1.y, f1.z, f1.w));
        xb[1] = cat8(pk4r(f2.x, f2.y, f2.z, f2.w), pk4r(f3.x, f3.y, f3.z, f3.w));
    }
    // Q^T = Wq . X^T
    f32x4 qacc[4];
    #pragma unroll
    for (int t = 0; t < 4; ++t) {
        const unsigned short* wr = Wq_p + (t * 16 + l15) * 64 + q4 * 16;
        short8 w0 = *(const short8*)(wr);
        short8 w1 = *(const short8*)(wr + 8);
        qacc[t] = MFMA16(w1, xb[1], MFMA16(w0, xb[0], zero));
    }
    short8 qb[2];
    {
        bf16x4 q4s[4];
        #pragma unroll
        for (int t = 0; t < 4; ++t) {
            float4 bqv = *(const float4*)(bq + t * 16 + q4 * 4);
            q4s[t] = pk4r((qacc[t][0] + bqv.x) * 0.125f, (qacc[t][1] + bqv.y) * 0.125f,
                          (qacc[t][2] + bqv.z) * 0.125f, (qacc[t][3] + bqv.w) * 0.125f);
        }
        qb[0] = cat8(q4s[0], q4s[1]);
        qb[1] = cat8(q4s[2], q4s[3]);
    }

    __syncthreads();   // K/V staged

    // S^T = K . Q^T  (K from LDS)
    const int rotk = (l15 & 7) * 16;
    f32x4 sacc[16];
    #pragma unroll
    for (int t = 0; t < 16; ++t) {
        const char* rbase = (const char*)Klds + (t * 16 + l15) * 128;
        short8 k0 = *(const short8*)(rbase + ((q4 * 32 + rotk) & 127));
        short8 k1 = *(const short8*)(rbase + ((q4 * 32 + 16 + rotk) & 127));
        sacc[t] = MFMA16(k1, qb[1], MFMA16(k0, qb[0], zero));
    }
    // softmax (query m = l15; reduce regs + q4 group)
    float mx = -1e30f;
    #pragma unroll
    for (int t = 0; t < 16; ++t)
        #pragma unroll
        for (int r = 0; r < 4; ++r) mx = fmaxf(mx, sacc[t][r]);
    mx = fmaxf(mx, __shfl_xor(mx, 16));
    mx = fmaxf(mx, __shfl_xor(mx, 32));
    float sm = 0.f;
    #pragma unroll
    for (int t = 0; t < 16; ++t)
        #pragma unroll
        for (int r = 0; r < 4; ++r) {
            float p = __expf(sacc[t][r] - mx);
            sacc[t][r] = p;
            sm += p;
        }
    sm += __shfl_xor(sm, 16);
    sm += __shfl_xor(sm, 32);
    const float inv = 1.f / sm;
    short8 pb[8];
    #pragma unroll
    for (int u = 0; u < 8; ++u)
        pb[u] = cat8(pk4r(sacc[2*u][0],   sacc[2*u][1],   sacc[2*u][2],   sacc[2*u][3]),
                     pk4r(sacc[2*u+1][0], sacc[2*u+1][1], sacc[2*u+1][2], sacc[2*u+1][3]));
    // O^T = V^T . P^T  (V from LDS)
    short8 ob[2];
    {
        bf16x4 o4s[4];
        #pragma unroll
        for (int dt = 0; dt < 4; ++dt) {
            const char* rbase = (const char*)Vlds + (dt * 16 + l15) * 512;
            f32x4 acc = zero;
            #pragma unroll
            for (int u = 0; u < 8; ++u) {
                short8 vf = *(const short8*)(rbase + ((q4 * 128 + u * 16 + rotk) & 511));
                acc = MFMA16(vf, pb[u], acc);
            }
            o4s[dt] = pk4r(acc[0] * inv, acc[1] * inv, acc[2] * inv, acc[3] * inv);
        }
        ob[0] = cat8(o4s[0], o4s[1]);
        ob[1] = cat8(o4s[2], o4s[3]);
    }
    // out^T = Wo . O^T
    float* orow = out + (size_t)(m0 + l15) * 64 + q4 * 4;
    #pragma unroll
    for (int et = 0; et < 4; ++et) {
        const unsigned short* wr = Wo_p + (et * 16 + l15) * 64 + q4 * 16;
        short8 w0 = *(const short8*)(wr);
        short8 w1 = *(const short8*)(wr + 8);
        f32x4 acc = MFMA16(w1, ob[1], MFMA16(w0, ob[0], zero));
        float4 bov = *(const float4*)(bo + et * 16 + q4 * 4);
        float4 res = { acc[0] + bov.x, acc[1] + bov.y, acc[2] + bov.z, acc[3] + bov.w };
        *(float4*)(orow + et * 16) = res;
    }
}

extern "C" void kernel_launch(void* const* d_in, const int* in_sizes, int n_in,
                              void* d_out, int out_size, void* d_ws, size_t ws_size,
                              hipStream_t stream) {
    const float* inp     = (const float*)d_in[0];
    const float* Wq      = (const float*)d_in[1];
    const float* bq      = (const float*)d_in[2];
    const float* Wkv     = (const float*)d_in[3];
    const float* bkv     = (const float*)d_in[4];
    const float* Wo      = (const float*)d_in[5];
    const float* bo      = (const float*)d_in[6];
    const float* conv_w  = (const float*)d_in[7];
    const float* conv_b  = (const float*)d_in[8];
    const float* gamma   = (const float*)d_in[9];
    const float* beta    = (const float*)d_in[10];

    char* ws = (char*)d_ws;
    unsigned short* Kb    = (unsigned short*)(ws);                 // 512 KiB
    unsigned short* Vt    = (unsigned short*)(ws + 524288);        // 512 KiB
    unsigned short* Wq_p  = (unsigned short*)(ws + 1048576);       // 8 KiB
    unsigned short* Wo_p  = (unsigned short*)(ws + 1056768);       // 8 KiB
    unsigned short* Wc_f  = (unsigned short*)(ws + 1064960);       // 512 KiB
    unsigned short* Wkv_f = (unsigned short*)(ws + 1589248);       // 32 KiB

    prep_kernel<<<1120, 256, 0, stream>>>(Wq, Wo, conv_w, Wkv, Wq_p, Wo_p, Wc_f, Wkv_f);
    kv_fused<<<256, 256, 0, stream>>>(inp, Wc_f, conv_b, gamma, beta, Wkv_f, bkv, Kb, Vt);
    attn_mfma<<<2048, 512, 0, stream>>>(inp, Wq_p, bq, Kb, Vt, Wo_p, bo, (float*)d_out);
}